// Round 14
// baseline (437.818 us; speedup 1.0000x reference)
//
#include <hip/hip_runtime.h>
#include <hip/hip_bf16.h>
#include <math.h>

typedef unsigned short u16;
typedef __attribute__((ext_vector_type(8))) short short8;
typedef __attribute__((ext_vector_type(4))) float f32x4;

constexpr int B_ = 8, T_ = 832, D_ = 1024, H_ = 16, HID_ = 4096, NB_ = 576;
constexpr int NT_ = B_ * T_;   // 6656 tokens

// ---- bf16 bit helpers (RNE) ----
__device__ inline u16 f2b(float f) {
    union { float f; unsigned u; } x{f};
    unsigned r = (x.u + 0x7FFFu + ((x.u >> 16) & 1u)) >> 16;
    return (u16)r;
}
__device__ inline float b2f(u16 b) {
    union { unsigned u; float f; } x; x.u = ((unsigned)b) << 16; return x.f;
}

// inline erf (Abramowitz-Stegun 7.1.26, |err| < 1.5e-7), no libcall
__device__ inline float erf_inl(float x) {
    float ax = fabsf(x);
    float t = __frcp_rn(1.0f + 0.3275911f * ax);
    float p = 1.061405429f;
    p = p * t - 1.453152027f;
    p = p * t + 1.421413741f;
    p = p * t - 0.284496736f;
    p = p * t + 0.254829592f;
    p = p * t;
    float e = 1.0f - p * __expf(-ax * ax);
    return copysignf(e, x);
}

__device__ inline void gload_lds16(const void* g, void* l) {
    __builtin_amdgcn_global_load_lds((const __attribute__((address_space(1))) void*)g,
                                     (__attribute__((address_space(3))) void*)l, 16, 0, 0);
}

// ---- merged weight transpose: all four weights, flat grid ----
__global__ __launch_bounds__(256) void wtrans_all(const float* __restrict__ wq,
                                                  const float* __restrict__ wp,
                                                  const float* __restrict__ w1,
                                                  const float* __restrict__ w2,
                                                  u16* __restrict__ oq, u16* __restrict__ op,
                                                  u16* __restrict__ o1, u16* __restrict__ o2) {
    __shared__ u16 tile[32][34];
    int bid = blockIdx.x;
    const float* in; u16* out; int K, N, idx;
    if (bid < 3072)      { in = wq; out = oq; K = 1024; N = 3072; idx = bid; }
    else if (bid < 4096) { in = wp; out = op; K = 1024; N = 1024; idx = bid - 3072; }
    else if (bid < 8192) { in = w1; out = o1; K = 1024; N = 4096; idx = bid - 4096; }
    else                 { in = w2; out = o2; K = 4096; N = 1024; idx = bid - 8192; }
    int nx = N >> 5;
    int n0 = (idx % nx) * 32, k0 = (idx / nx) * 32;
    int tx = threadIdx.x & 31, ty = threadIdx.x >> 5;
    for (int i = 0; i < 4; i++) {
        int k = k0 + ty + i * 8;
        tile[ty + i * 8][tx] = f2b(in[(size_t)k * N + n0 + tx]);
    }
    __syncthreads();
    for (int i = 0; i < 4; i++) {
        int n = n0 + ty + i * 8;
        out[(size_t)n * K + k0 + tx] = tile[tx][ty + i * 8];
    }
}

// ---- LayerNorm: f32 in -> bf16 out, one block per row (D=1024, 256 thr) ----
__global__ __launch_bounds__(256) void ln_kernel(const float* __restrict__ x,
                                                 const float* __restrict__ g,
                                                 const float* __restrict__ bt,
                                                 u16* __restrict__ out) {
    int row = blockIdx.x, tid = threadIdx.x;
    float4 v = ((const float4*)(x + (size_t)row * D_))[tid];
    float s = v.x + v.y + v.z + v.w;
    float q = v.x * v.x + v.y * v.y + v.z * v.z + v.w * v.w;
    for (int o = 1; o < 64; o <<= 1) { s += __shfl_xor(s, o); q += __shfl_xor(q, o); }
    __shared__ float red[4][2];
    if ((tid & 63) == 0) { red[tid >> 6][0] = s; red[tid >> 6][1] = q; }
    __syncthreads();
    s = red[0][0] + red[1][0] + red[2][0] + red[3][0];
    q = red[0][1] + red[1][1] + red[2][1] + red[3][1];
    float mean = s * (1.0f / D_);
    float var = q * (1.0f / D_) - mean * mean;
    float inv = rsqrtf(fmaxf(var, 0.f) + 1e-6f);
    float4 gv = ((const float4*)g)[tid];
    float4 bv = ((const float4*)bt)[tid];
    u16* orow = out + (size_t)row * D_ + tid * 4;
    orow[0] = f2b((v.x - mean) * inv * gv.x + bv.x);
    orow[1] = f2b((v.y - mean) * inv * gv.y + bv.y);
    orow[2] = f2b((v.z - mean) * inv * gv.z + bv.z);
    orow[3] = f2b((v.w - mean) * inv * gv.w + bv.w);
}

// ---- gemm6: double-buffered pipelined GEMM ----
// BK=32, 2 LDS buffers. Configs:
//   <128,256,2,4>: per-wave 64x64, 48KB -> 3 blocks/CU. K=1024 big GEMMs.
//   <128,64,2,1>:  per-wave 64x64, 2-wave blocks, 24KB -> 6 blocks/CU;
//                  grid 832 (3.25 blocks/CU) fixes the 416-block tail
//                  imbalance of N=1024 GEMMs (proj, FC2).
// launch_bounds 2nd arg = min waves per EU (round-11 lesson).
// Ledger: stage(t+1) at head into buf^1 (WAR-safe via end-of-(t-1) barrier);
// vmcnt(0)+barrier at end of each iter. Pair-row XOR swizzle
// idx^=((row>>1)&7)<<3 on stage source + read offsets (HW-verified 0-conflict).
// MODE 0: bf16 out. MODE 1: f32 out + f32 residual. MODE 2: exact GELU, bf16 out.
template<int BM, int BN, int WR, int WC, int MODE>
__global__ __launch_bounds__(WR * WC * 64, (WR * WC == 8) ? 2 : 3)
void gemm6(const u16* __restrict__ A, const u16* __restrict__ Bt,
           const float* __restrict__ bias, const float* __restrict__ resid,
           void* __restrict__ outp, int M, int N, int K) {
    constexpr int THREADS = WR * WC * 64;
    constexpr int MF = BM / WR / 16;
    constexpr int NF = BN / WC / 16;
    constexpr int NROWS = BM + BN;
    constexpr int CHUNKS = NROWS * 4 / THREADS;
    constexpr int LDSU = NROWS * 32;
    __shared__ u16 lds_[2 * LDSU];

    int tid = threadIdx.x, l = tid & 63, w = tid >> 6;
    int lrow = l & 15, lgrp = l >> 4;
    int wr = w / WC, wc = w % WC;

    // XCD-aware bijective block swizzle (all grids are multiples of 8)
    int nwg = gridDim.x * gridDim.y;
    int bid = blockIdx.y * gridDim.x + blockIdx.x;
    int cpx = nwg >> 3;
    int swz = (bid & 7) * cpx + (bid >> 3);
    int bx = swz % gridDim.x, by = swz / gridDim.x;
    int m0 = by * BM, n0 = bx * BN;

    // stage sources: physical chunk c holds logical chunk lc (pair-row swizzle)
    const u16* src[CHUNKS];
    int ldst[CHUNKS];
#pragma unroll
    for (int i = 0; i < CHUNKS; i++) {
        int c = i * THREADS + tid;
        int lc = (c & ~7) | ((c ^ (c >> 3)) & 7);
        int row = lc >> 2, colu = (lc & 3) * 8;
        src[i] = (row < BM) ? A + (size_t)(m0 + row) * K + colu
                            : Bt + (size_t)(n0 + row - BM) * K + colu;
        ldst[i] = c * 8;   // linear LDS dest (wave-uniform base + lane*16B)
    }

#define STAGE6(bufi, kt)                                                    \
    do {                                                                    \
        int kof = (kt) * 32;                                                \
        u16* bb = lds_ + (bufi) * LDSU;                                     \
        _Pragma("unroll")                                                   \
        for (int i = 0; i < CHUNKS; i++) gload_lds16(src[i] + kof, bb + ldst[i]); \
    } while (0)

    f32x4 acc[MF][NF];
#pragma unroll
    for (int m = 0; m < MF; m++)
#pragma unroll
        for (int n = 0; n < NF; n++) acc[m][n] = (f32x4){0, 0, 0, 0};

    // swizzled frag read offsets (u16 idx)
    int aidx[MF], bidx[NF];
#pragma unroll
    for (int m = 0; m < MF; m++) {
        int row = wr * (BM / WR) + m * 16 + lrow;
        aidx[m] = (row * 32 + lgrp * 8) ^ (((row >> 1) & 7) << 3);
    }
#pragma unroll
    for (int n = 0; n < NF; n++) {
        int row = BM + wc * (BN / WC) + n * 16 + lrow;
        bidx[n] = (row * 32 + lgrp * 8) ^ (((row >> 1) & 7) << 3);
    }

    int nkt = K >> 5;
    STAGE6(0, 0);
    asm volatile("s_waitcnt vmcnt(0)" ::: "memory");
    asm volatile("s_barrier" ::: "memory");

    for (int t = 0; t < nkt; ++t) {
        if (t + 1 < nkt) STAGE6((t + 1) & 1, t + 1);

        const u16* bp = lds_ + (t & 1) * LDSU;
        short8 af[MF], bfr[NF];
#pragma unroll
        for (int m = 0; m < MF; m++) af[m] = *(const short8*)(bp + aidx[m]);
#pragma unroll
        for (int n = 0; n < NF; n++) bfr[n] = *(const short8*)(bp + bidx[n]);

        __builtin_amdgcn_s_setprio(1);
#pragma unroll
        for (int m = 0; m < MF; m++)
#pragma unroll
            for (int n = 0; n < NF; n++)
                acc[m][n] = __builtin_amdgcn_mfma_f32_16x16x32_bf16(af[m], bfr[n], acc[m][n], 0, 0, 0);
        __builtin_amdgcn_s_setprio(0);

        if (t + 1 < nkt) {
            asm volatile("s_waitcnt vmcnt(0)" ::: "memory");
            asm volatile("s_barrier" ::: "memory");
        }
    }
#undef STAGE6

#pragma unroll
    for (int m = 0; m < MF; m++) {
        int rbase = m0 + wr * (BM / WR) + m * 16 + lgrp * 4;
#pragma unroll
        for (int n = 0; n < NF; n++) {
            int col = n0 + wc * (BN / WC) + n * 16 + lrow;
            float bv = bias[col];
#pragma unroll
            for (int j = 0; j < 4; j++) {
                int row = rbase + j;
                float v = acc[m][n][j] + bv;
                size_t off = (size_t)row * N + col;
                if constexpr (MODE == 0) {
                    ((u16*)outp)[off] = f2b(v);
                } else if constexpr (MODE == 1) {
                    ((float*)outp)[off] = v + resid[off];
                } else {
                    float gl = 0.5f * v * (1.0f + erf_inl(v * 0.70710678118654752f));
                    ((u16*)outp)[off] = f2b(gl);
                }
            }
        }
    }
}

// ---- V transpose: qkv[B*T, 3072] v-part -> vt[B,H,64,T] ----
__global__ __launch_bounds__(256) void vtrans_kernel(const u16* __restrict__ qkv,
                                                     u16* __restrict__ vt) {
    __shared__ u16 tile[32][66];
    int bh = blockIdx.y, b = bh >> 4, h = bh & 15;
    int t0 = blockIdx.x * 32;
    int dx = threadIdx.x & 63, ty = threadIdx.x >> 6;
    for (int i = 0; i < 8; i++) {
        int tt = ty * 8 + i;
        tile[tt][dx] = qkv[(size_t)(b * T_ + t0 + tt) * 3072 + 2048 + h * 64 + dx];
    }
    __syncthreads();
    int tx = threadIdx.x & 31, dy = threadIdx.x >> 5;
    for (int i = 0; i < 8; i++) {
        int d = dy * 8 + i;
        vt[((size_t)bh * 64 + d) * T_ + t0 + tx] = tile[tx][d];
    }
}

// ---- flash attention: 8 waves x 16 q-rows (QBLK=128), 64-key LDS tiles,
// double-buffered K/V stage + mask prefetched one tile ahead into registers.
__global__ __launch_bounds__(512, 4) void attn_kernel(const u16* __restrict__ qkv,
                                                      const u16* __restrict__ vt,
                                                      const float* __restrict__ mask,
                                                      u16* __restrict__ obuf) {
    __shared__ u16 Ks[2][4096];
    __shared__ u16 Vs[2][4096];
    __shared__ u16 Ps[8][1024];
    int qt = blockIdx.x, bh = blockIdx.y, b = bh >> 4, h = bh & 15;
    int tid = threadIdx.x, w = tid >> 6, l = tid & 63;
    int lrow = l & 15, lgrp = l >> 4;

    int qrow = qt * 128 + w * 16 + lrow;
    int qrc = qrow < T_ ? qrow : T_ - 1;
    const u16* qp = qkv + (size_t)(b * T_ + qrc) * 3072 + h * 64 + lgrp * 8;
    short8 aq0, aq1;
    {
        short8 r0 = *(const short8*)qp;
        short8 r1 = *(const short8*)(qp + 32);
        for (int i = 0; i < 8; i++) {
            aq0[i] = (short)f2b(b2f((u16)r0[i]) * 0.125f);
            aq1[i] = (short)f2b(b2f((u16)r1[i]) * 0.125f);
        }
    }

    int tq0 = qt * 128 + w * 16 + lgrp * 4;
    bool qvalid = tq0 < T_;
    const float* mrowp[4];
#pragma unroll
    for (int j = 0; j < 4; j++) {
        int tq = tq0 + j; if (tq >= T_) tq = T_ - 1;
        mrowp[j] = mask + (size_t)tq * T_;
    }

    float m_r[4], l_r[4];
    f32x4 oacc[4];
    for (int j = 0; j < 4; j++) { m_r[j] = -1e30f; l_r[j] = 0.f; }
    for (int n = 0; n < 4; n++) oacc[n] = (f32x4){0, 0, 0, 0};

    int srow = tid >> 3, sp = tid & 7;
    int se = (sp ^ (srow & 7)) * 8;
    const u16* kbase = qkv + (size_t)b * T_ * 3072 + 1024 + h * 64;
    const u16* vbase = vt + (size_t)bh * 64 * T_;

#define STAGE_KV(buf, kk0)                                                        \
    do {                                                                          \
        gload_lds16(kbase + (size_t)((kk0) + srow) * 3072 + se, &Ks[buf][w * 512]); \
        gload_lds16(vbase + (size_t)srow * T_ + (kk0) + se, &Vs[buf][w * 512]);     \
    } while (0)

    float mc[16], mn[16];
    STAGE_KV(0, 0);
#pragma unroll
    for (int j = 0; j < 4; j++)
#pragma unroll
        for (int c = 0; c < 4; c++)
            mc[j * 4 + c] = mrowp[j][c * 16 + lrow];
    __syncthreads();

    int cur = 0;
    u16* Pw = Ps[w];
    int swl = lrow & 7;
    int slot0 = (lgrp ^ swl) * 8, slot1 = ((lgrp + 4) ^ swl) * 8;

    for (int kt = 0; kt < 13; ++kt) {
        int kk0 = kt * 64;
        if (kt < 12) {
            STAGE_KV(cur ^ 1, kk0 + 64);
#pragma unroll
            for (int j = 0; j < 4; j++)
#pragma unroll
                for (int c = 0; c < 4; c++)
                    mn[j * 4 + c] = mrowp[j][kk0 + 64 + c * 16 + lrow];
        }

        f32x4 sc[4];
        for (int c = 0; c < 4; c++) sc[c] = (f32x4){0, 0, 0, 0};
        const u16* Kb = Ks[cur];
        __builtin_amdgcn_s_setprio(1);
        for (int c = 0; c < 4; c++) {
            const u16* krow = Kb + (c * 16 + lrow) * 64;
            short8 bk0 = *(const short8*)(krow + slot0);
            short8 bk1 = *(const short8*)(krow + slot1);
            sc[c] = __builtin_amdgcn_mfma_f32_16x16x32_bf16(aq0, bk0, sc[c], 0, 0, 0);
            sc[c] = __builtin_amdgcn_mfma_f32_16x16x32_bf16(aq1, bk1, sc[c], 0, 0, 0);
        }
        __builtin_amdgcn_s_setprio(0);

        int lo3 = lrow & 7, hi = lrow >> 3;
#pragma unroll
        for (int j = 0; j < 4; j++) {
            float s0 = sc[0][j] + mc[j * 4 + 0];
            float s1 = sc[1][j] + mc[j * 4 + 1];
            float s2 = sc[2][j] + mc[j * 4 + 2];
            float s3 = sc[3][j] + mc[j * 4 + 3];
            float mx = fmaxf(fmaxf(s0, s1), fmaxf(s2, s3));
            mx = fmaxf(mx, __shfl_xor(mx, 1));
            mx = fmaxf(mx, __shfl_xor(mx, 2));
            mx = fmaxf(mx, __shfl_xor(mx, 4));
            mx = fmaxf(mx, __shfl_xor(mx, 8));
            float mnew = fmaxf(m_r[j], mx);
            float scf = __expf(m_r[j] - mnew);
            float p0 = __expf(s0 - mnew), p1 = __expf(s1 - mnew);
            float p2 = __expf(s2 - mnew), p3 = __expf(s3 - mnew);
            float ps = (p0 + p1) + (p2 + p3);
            ps += __shfl_xor(ps, 1); ps += __shfl_xor(ps, 2);
            ps += __shfl_xor(ps, 4); ps += __shfl_xor(ps, 8);
            l_r[j] = l_r[j] * scf + ps;
            m_r[j] = mnew;
            for (int n = 0; n < 4; n++) oacc[n][j] *= scf;
            int row_p = lgrp * 4 + j, swp = row_p & 7;
            u16* pr = Pw + row_p * 64;
            pr[((hi ^ swp) * 8) + lo3]       = f2b(p0);
            pr[(((2 + hi) ^ swp) * 8) + lo3] = f2b(p1);
            pr[(((4 + hi) ^ swp) * 8) + lo3] = f2b(p2);
            pr[(((6 + hi) ^ swp) * 8) + lo3] = f2b(p3);
        }

        short8 ap0 = *(const short8*)&Pw[lrow * 64 + slot0];
        short8 ap1 = *(const short8*)&Pw[lrow * 64 + slot1];
        const u16* Vb = Vs[cur];
        __builtin_amdgcn_s_setprio(1);
        for (int n = 0; n < 4; n++) {
            const u16* vrow = Vb + (n * 16 + lrow) * 64;
            short8 bv0 = *(const short8*)(vrow + slot0);
            short8 bv1 = *(const short8*)(vrow + slot1);
            oacc[n] = __builtin_amdgcn_mfma_f32_16x16x32_bf16(ap0, bv0, oacc[n], 0, 0, 0);
            oacc[n] = __builtin_amdgcn_mfma_f32_16x16x32_bf16(ap1, bv1, oacc[n], 0, 0, 0);
        }
        __builtin_amdgcn_s_setprio(0);

        __syncthreads();
#pragma unroll
        for (int i = 0; i < 16; i++) mc[i] = mn[i];
        cur ^= 1;
    }
#undef STAGE_KV

    if (qvalid) {
        for (int j = 0; j < 4; j++) {
            float inv = 1.0f / l_r[j];
            int t = tq0 + j;
            for (int n = 0; n < 4; n++)
                obuf[(size_t)(b * T_ + t) * 1024 + h * 64 + n * 16 + lrow] = f2b(oacc[n][j] * inv);
        }
    }
}

// ---- LoRA: per (b, group of 16 tokens) add (z @ A_e @ B_e)/R into out ----
__global__ __launch_bounds__(256) void lora_kernel(const u16* __restrict__ snorm,
                                                   const float* __restrict__ lA,
                                                   const float* __restrict__ lB,
                                                   const int* __restrict__ idx,
                                                   float* __restrict__ outp) {
    __shared__ float down[16][8];
    int blk = blockIdx.x, b = blk >> 4, kk = blk & 15;
    int e = idx[kk];
    int tok0 = b * T_ + NB_ + kk * 16;
    int tid = threadIdx.x;
    {
        int m = tid >> 4;            // 0..15
        int r = (tid >> 1) & 7;      // 0..7
        int dh = tid & 1;            // 0..1
        const u16* z = snorm + (size_t)(tok0 + m) * D_ + dh * 512;
        const float* Ae = lA + (size_t)e * D_ * 8 + (size_t)(dh * 512) * 8 + r;
        float acc = 0.f;
        for (int d = 0; d < 512; ++d) acc += b2f(z[d]) * Ae[(size_t)d * 8];
        acc += __shfl_xor(acc, 1);
        if (dh == 0) down[m][r] = acc;
    }
    __syncthreads();
    for (int ci = 0; ci < 4; ci++) {
        int col = tid + ci * 256;
        float br[8];
        for (int r = 0; r < 8; r++) br[r] = lB[((size_t)e * 8 + r) * D_ + col];
        for (int m = 0; m < 16; m++) {
            float acc = 0.f;
            for (int r = 0; r < 8; r++) acc += down[m][r] * br[r];
            outp[(size_t)(tok0 + m) * D_ + col] += acc * 0.125f;
        }
    }
}

extern "C" void kernel_launch(void* const* d_in, const int* in_sizes, int n_in,
                              void* d_out, int out_size, void* d_ws, size_t ws_size,
                              hipStream_t stream) {
    const float* s      = (const float*)d_in[0];
    const float* mask   = (const float*)d_in[1];
    const float* g1     = (const float*)d_in[2];
    const float* b1     = (const float*)d_in[3];
    const float* w_qkv  = (const float*)d_in[4];
    const float* b_qkv  = (const float*)d_in[5];
    const float* w_proj = (const float*)d_in[6];
    const float* b_proj = (const float*)d_in[7];
    const float* g2     = (const float*)d_in[8];
    const float* b2     = (const float*)d_in[9];
    const float* w_fc1  = (const float*)d_in[10];
    const float* b_fc1  = (const float*)d_in[11];
    const float* w_fc2  = (const float*)d_in[12];
    const float* b_fc2  = (const float*)d_in[13];
    const float* lA     = (const float*)d_in[14];
    const float* lB     = (const float*)d_in[15];
    const int*   eidx   = (const int*)d_in[16];
    float* out = (float*)d_out;
    char* ws = (char*)d_ws;

    // workspace layout (max 115 MB, lifetime-based reuse)
    u16*   wqkvT = (u16*)(ws + 0);            // 6.0 MB
    u16*   wprojT= (u16*)(ws + 6291456);      // 2.0 MB
    u16*   wfc1T = (u16*)(ws + 8388608);      // 8.0 MB
    u16*   wfc2T = (u16*)(ws + 16777216);     // 8.0 MB
    float* s1    = (float*)(ws + 25165824);   // 26 MB f32, ends 50 MB
    u16*   xln   = (u16*)(ws + 52428800);     // 13 MB (x_ln -> o -> s_norm)
    u16*   vt    = (u16*)(ws + 66060288);     // 13 MB (v_t; dead after attn)
    u16*   qkv   = (u16*)(ws + 79691776);     // 39 MB (qkv; dead after attn)
    u16*   h     = (u16*)(ws + 66060288);     // 54.5 MB (overwrites vt+qkv), ends ~115 MB

    wtrans_all<<<12288, 256, 0, stream>>>(w_qkv, w_proj, w_fc1, w_fc2,
                                          wqkvT, wprojT, wfc1T, wfc2T);
    ln_kernel<<<NT_, 256, 0, stream>>>(s, g1, b1, xln);
    gemm6<128, 256, 2, 4, 0><<<dim3(3072 / 256, NT_ / 128), 512, 0, stream>>>(xln, wqkvT, b_qkv, nullptr, qkv, NT_, 3072, 1024);
    vtrans_kernel<<<dim3(26, 128), 256, 0, stream>>>(qkv, vt);
    attn_kernel<<<dim3(7, 128), 512, 0, stream>>>(qkv, vt, mask, xln);
    gemm6<128, 64, 2, 1, 1><<<dim3(1024 / 64, NT_ / 128), 128, 0, stream>>>(xln, wprojT, b_proj, s, s1, NT_, 1024, 1024);
    ln_kernel<<<NT_, 256, 0, stream>>>(s1, g2, b2, xln);
    gemm6<128, 256, 2, 4, 2><<<dim3(4096 / 256, NT_ / 128), 512, 0, stream>>>(xln, wfc1T, b_fc1, nullptr, h, NT_, 4096, 1024);
    gemm6<128, 64, 2, 1, 1><<<dim3(1024 / 64, NT_ / 128), 128, 0, stream>>>(h, wfc2T, b_fc2, s1, out, NT_, 1024, 4096);
    lora_kernel<<<128, 256, 0, stream>>>(xln, lA, lB, eidx, out);
}

// Round 15
// 405.474 us; speedup vs baseline: 1.0798x; 1.0798x over previous
//
#include <hip/hip_runtime.h>
#include <hip/hip_bf16.h>
#include <math.h>

typedef unsigned short u16;
typedef __attribute__((ext_vector_type(8))) short short8;
typedef __attribute__((ext_vector_type(4))) float f32x4;

constexpr int B_ = 8, T_ = 832, D_ = 1024, H_ = 16, HID_ = 4096, NB_ = 576;
constexpr int NT_ = B_ * T_;   // 6656 tokens

// ---- bf16 bit helpers (RNE) ----
__device__ inline u16 f2b(float f) {
    union { float f; unsigned u; } x{f};
    unsigned r = (x.u + 0x7FFFu + ((x.u >> 16) & 1u)) >> 16;
    return (u16)r;
}
__device__ inline float b2f(u16 b) {
    union { unsigned u; float f; } x; x.u = ((unsigned)b) << 16; return x.f;
}

// inline erf (Abramowitz-Stegun 7.1.26, |err| < 1.5e-7), no libcall
__device__ inline float erf_inl(float x) {
    float ax = fabsf(x);
    float t = __frcp_rn(1.0f + 0.3275911f * ax);
    float p = 1.061405429f;
    p = p * t - 1.453152027f;
    p = p * t + 1.421413741f;
    p = p * t - 0.284496736f;
    p = p * t + 0.254829592f;
    p = p * t;
    float e = 1.0f - p * __expf(-ax * ax);
    return copysignf(e, x);
}

__device__ inline void gload_lds16(const void* g, void* l) {
    __builtin_amdgcn_global_load_lds((const __attribute__((address_space(1))) void*)g,
                                     (__attribute__((address_space(3))) void*)l, 16, 0, 0);
}

// ---- merged weight transpose: all four weights, flat grid ----
__global__ __launch_bounds__(256) void wtrans_all(const float* __restrict__ wq,
                                                  const float* __restrict__ wp,
                                                  const float* __restrict__ w1,
                                                  const float* __restrict__ w2,
                                                  u16* __restrict__ oq, u16* __restrict__ op,
                                                  u16* __restrict__ o1, u16* __restrict__ o2) {
    __shared__ u16 tile[32][34];
    int bid = blockIdx.x;
    const float* in; u16* out; int K, N, idx;
    if (bid < 3072)      { in = wq; out = oq; K = 1024; N = 3072; idx = bid; }
    else if (bid < 4096) { in = wp; out = op; K = 1024; N = 1024; idx = bid - 3072; }
    else if (bid < 8192) { in = w1; out = o1; K = 1024; N = 4096; idx = bid - 4096; }
    else                 { in = w2; out = o2; K = 4096; N = 1024; idx = bid - 8192; }
    int nx = N >> 5;
    int n0 = (idx % nx) * 32, k0 = (idx / nx) * 32;
    int tx = threadIdx.x & 31, ty = threadIdx.x >> 5;
    for (int i = 0; i < 4; i++) {
        int k = k0 + ty + i * 8;
        tile[ty + i * 8][tx] = f2b(in[(size_t)k * N + n0 + tx]);
    }
    __syncthreads();
    for (int i = 0; i < 4; i++) {
        int n = n0 + ty + i * 8;
        out[(size_t)n * K + k0 + tx] = tile[tx][ty + i * 8];
    }
}

// ---- LayerNorm: f32 in -> bf16 out, one block per row (D=1024, 256 thr) ----
__global__ __launch_bounds__(256) void ln_kernel(const float* __restrict__ x,
                                                 const float* __restrict__ g,
                                                 const float* __restrict__ bt,
                                                 u16* __restrict__ out) {
    int row = blockIdx.x, tid = threadIdx.x;
    float4 v = ((const float4*)(x + (size_t)row * D_))[tid];
    float s = v.x + v.y + v.z + v.w;
    float q = v.x * v.x + v.y * v.y + v.z * v.z + v.w * v.w;
    for (int o = 1; o < 64; o <<= 1) { s += __shfl_xor(s, o); q += __shfl_xor(q, o); }
    __shared__ float red[4][2];
    if ((tid & 63) == 0) { red[tid >> 6][0] = s; red[tid >> 6][1] = q; }
    __syncthreads();
    s = red[0][0] + red[1][0] + red[2][0] + red[3][0];
    q = red[0][1] + red[1][1] + red[2][1] + red[3][1];
    float mean = s * (1.0f / D_);
    float var = q * (1.0f / D_) - mean * mean;
    float inv = rsqrtf(fmaxf(var, 0.f) + 1e-6f);
    float4 gv = ((const float4*)g)[tid];
    float4 bv = ((const float4*)bt)[tid];
    u16* orow = out + (size_t)row * D_ + tid * 4;
    orow[0] = f2b((v.x - mean) * inv * gv.x + bv.x);
    orow[1] = f2b((v.y - mean) * inv * gv.y + bv.y);
    orow[2] = f2b((v.z - mean) * inv * gv.z + bv.z);
    orow[3] = f2b((v.w - mean) * inv * gv.w + bv.w);
}

// ---- gemm5: 256x256 tile, BK=64, 8 waves (2M x 4N), per-wave 128x64 output.
// Double-buffered 128KB LDS; one vmcnt(0)+s_barrier per K-tile.
// Row = 128B: slot^=(row&7) 16B-granule swizzle (attn-verified 0-conflict),
// applied as inverse on the global stage source (LDS dest stays linear).
// MODE 0: bf16 out. MODE 2: exact GELU, bf16 out.
template<int MODE>
__global__ __launch_bounds__(512, 2)
void gemm5(const u16* __restrict__ A, const u16* __restrict__ Bt,
           const float* __restrict__ bias, void* __restrict__ outp,
           int M, int N, int K) {
    __shared__ u16 lds5[2][32768];   // [buf][A 16384 | B 16384] u16
    int tid = threadIdx.x, l = tid & 63, w = tid >> 6;
    int lrow = l & 15, lgrp = l >> 4;
    int wr = w >> 2, wc = w & 3;

    // XCD-aware bijective block swizzle (grids are multiples of 8)
    int nwg = gridDim.x * gridDim.y;
    int bid = blockIdx.y * gridDim.x + blockIdx.x;
    int cpx = nwg >> 3;
    int swz = (bid & 7) * cpx + (bid >> 3);
    int bx = swz % gridDim.x, by = swz / gridDim.x;
    int m0 = by * 256, n0 = bx * 256;

    // stage: 4096 chunks of 16B per K-tile (A: c<2048, B: c>=2048), 8/thread.
    // chunk c -> row = (c&2047)>>3, phys slot = c&7, logical slot = phys^(row&7).
    const u16* src[8];
    int ldst[8];
#pragma unroll
    for (int i = 0; i < 8; i++) {
        int c = i * 512 + tid;
        int row = (c & 2047) >> 3;
        int ls = (c & 7) ^ (row & 7);
        src[i] = (c < 2048 ? A + (size_t)(m0 + row) * K : Bt + (size_t)(n0 + row) * K) + ls * 8;
        ldst[i] = c * 8;   // linear LDS dest (wave-uniform base + lane*16B)
    }

#define STAGE5(bufi, t)                                                      \
    do {                                                                     \
        int ko = (t) * 64;                                                   \
        u16* bb = &lds5[bufi][0];                                            \
        _Pragma("unroll")                                                    \
        for (int i = 0; i < 8; i++) gload_lds16(src[i] + ko, bb + ldst[i]);  \
    } while (0)

    f32x4 acc[8][4];
#pragma unroll
    for (int m = 0; m < 8; m++)
#pragma unroll
        for (int n = 0; n < 4; n++) acc[m][n] = (f32x4){0, 0, 0, 0};

    // frag read bases (u16 idx) + per-k-half swizzled slot offsets
    int sw = lrow & 7;
    int slot0 = (lgrp ^ sw) * 8, slot1 = ((4 + lgrp) ^ sw) * 8;
    int arow[8], brow[4];
#pragma unroll
    for (int m = 0; m < 8; m++) arow[m] = (wr * 128 + m * 16 + lrow) * 64;
#pragma unroll
    for (int n = 0; n < 4; n++) brow[n] = 16384 + (wc * 64 + n * 16 + lrow) * 64;

    int nkt = K >> 6;
    STAGE5(0, 0);
    asm volatile("s_waitcnt vmcnt(0)" ::: "memory");
    asm volatile("s_barrier" ::: "memory");

    for (int t = 0; t < nkt; ++t) {
        int ct = t & 1;
        if (t + 1 < nkt) STAGE5(ct ^ 1, t + 1);
        const u16* bp = &lds5[ct][0];
#pragma unroll
        for (int kh = 0; kh < 2; kh++) {
            int so = kh ? slot1 : slot0;
            short8 bf[4];
#pragma unroll
            for (int n = 0; n < 4; n++) bf[n] = *(const short8*)(bp + brow[n] + so);
#pragma unroll
            for (int mg = 0; mg < 2; mg++) {
                short8 af[4];
#pragma unroll
                for (int mi = 0; mi < 4; mi++) af[mi] = *(const short8*)(bp + arow[mg * 4 + mi] + so);
#pragma unroll
                for (int mi = 0; mi < 4; mi++)
#pragma unroll
                    for (int n = 0; n < 4; n++)
                        acc[mg * 4 + mi][n] =
                            __builtin_amdgcn_mfma_f32_16x16x32_bf16(af[mi], bf[n], acc[mg * 4 + mi][n], 0, 0, 0);
            }
        }
        if (t + 1 < nkt) asm volatile("s_waitcnt vmcnt(0)" ::: "memory");
        asm volatile("s_barrier" ::: "memory");
    }
#undef STAGE5

#pragma unroll
    for (int m = 0; m < 8; m++) {
        int rb = m0 + wr * 128 + m * 16 + lgrp * 4;
#pragma unroll
        for (int n = 0; n < 4; n++) {
            int col = n0 + wc * 64 + n * 16 + lrow;
            float bv = bias[col];
#pragma unroll
            for (int j = 0; j < 4; j++) {
                float v = acc[m][n][j] + bv;
                size_t off = (size_t)(rb + j) * N + col;
                if constexpr (MODE == 0) {
                    ((u16*)outp)[off] = f2b(v);
                } else {
                    float gl = 0.5f * v * (1.0f + erf_inl(v * 0.70710678118654752f));
                    ((u16*)outp)[off] = f2b(gl);
                }
            }
        }
    }
}

// ---- Pipelined GEMM (128-tiles): triple-buffered, depth-2 prefetch ----
template<int BM, int BN, int WR, int WC, int MODE>
__global__ __launch_bounds__(WR * WC * 64, (WR * WC == 8) ? 2 : 3)
void gemm3(const u16* __restrict__ A, const u16* __restrict__ Bt,
           const float* __restrict__ bias, const float* __restrict__ resid,
           void* __restrict__ outp, int M, int N, int K) {
    constexpr int THREADS = WR * WC * 64;
    constexpr int MF = BM / WR / 16;
    constexpr int NF = BN / WC / 16;
    constexpr int NROWS = BM + BN;
    constexpr int CHUNKS = NROWS * 4 / THREADS;
    constexpr int LDSU = NROWS * 32;
    __shared__ u16 lds_[3 * LDSU];

    int tid = threadIdx.x, l = tid & 63, w = tid >> 6;
    int lrow = l & 15, lgrp = l >> 4;
    int wr = w / WC, wc = w % WC;

    int nwg = gridDim.x * gridDim.y;
    int bid = blockIdx.y * gridDim.x + blockIdx.x;
    int cpx = nwg >> 3;
    int swz = (bid & 7) * cpx + (bid >> 3);
    int bx = swz % gridDim.x, by = swz / gridDim.x;
    int m0 = by * BM, n0 = bx * BN;

    const u16* src[CHUNKS];
    int ldst[CHUNKS];
#pragma unroll
    for (int i = 0; i < CHUNKS; i++) {
        int c = i * THREADS + tid;
        int lc = (c & ~7) | ((c ^ (c >> 3)) & 7);
        int row = lc >> 2, colu = (lc & 3) * 8;
        src[i] = (row < BM) ? A + (size_t)(m0 + row) * K + colu
                            : Bt + (size_t)(n0 + row - BM) * K + colu;
        ldst[i] = c * 8;
    }

#define STAGE3(bufi, kt)                                                    \
    do {                                                                    \
        int kof = (kt) * 32;                                                \
        u16* bb = lds_ + (bufi) * LDSU;                                     \
        _Pragma("unroll")                                                   \
        for (int i = 0; i < CHUNKS; i++) gload_lds16(src[i] + kof, bb + ldst[i]); \
    } while (0)

    f32x4 acc[MF][NF];
#pragma unroll
    for (int m = 0; m < MF; m++)
#pragma unroll
        for (int n = 0; n < NF; n++) acc[m][n] = (f32x4){0, 0, 0, 0};

    int aidx[MF], bidx[NF];
#pragma unroll
    for (int m = 0; m < MF; m++) {
        int row = wr * 64 + m * 16 + lrow;
        aidx[m] = (row * 32 + lgrp * 8) ^ (((row >> 1) & 7) << 3);
    }
#pragma unroll
    for (int n = 0; n < NF; n++) {
        int row = BM + wc * 64 + n * 16 + lrow;
        bidx[n] = (row * 32 + lgrp * 8) ^ (((row >> 1) & 7) << 3);
    }

    int nkt = K >> 5;
    STAGE3(0, 0);
    STAGE3(1, 1);
    if constexpr (CHUNKS == 3) asm volatile("s_waitcnt vmcnt(3)" ::: "memory");
    else                       asm volatile("s_waitcnt vmcnt(4)" ::: "memory");
    asm volatile("s_barrier" ::: "memory");

    int cur = 0;
    for (int t = 0; t < nkt; ++t) {
        int sb = cur + 2; if (sb >= 3) sb -= 3;
        if (t + 2 < nkt) STAGE3(sb, t + 2);

        const u16* bp = lds_ + cur * LDSU;
        short8 af[MF], bfr[NF];
#pragma unroll
        for (int m = 0; m < MF; m++) af[m] = *(const short8*)(bp + aidx[m]);
#pragma unroll
        for (int n = 0; n < NF; n++) bfr[n] = *(const short8*)(bp + bidx[n]);

        __builtin_amdgcn_s_setprio(1);
#pragma unroll
        for (int m = 0; m < MF; m++)
#pragma unroll
            for (int n = 0; n < NF; n++)
                acc[m][n] = __builtin_amdgcn_mfma_f32_16x16x32_bf16(af[m], bfr[n], acc[m][n], 0, 0, 0);
        __builtin_amdgcn_s_setprio(0);

        if (t + 2 < nkt) {
            if constexpr (CHUNKS == 3) asm volatile("s_waitcnt vmcnt(3)" ::: "memory");
            else                       asm volatile("s_waitcnt vmcnt(4)" ::: "memory");
        } else if (t + 1 < nkt) {
            asm volatile("s_waitcnt vmcnt(0)" ::: "memory");
        }
        asm volatile("s_barrier" ::: "memory");
        cur = cur + 1; if (cur == 3) cur = 0;
    }
#undef STAGE3

#pragma unroll
    for (int m = 0; m < MF; m++) {
        int rbase = m0 + wr * 64 + m * 16 + lgrp * 4;
#pragma unroll
        for (int n = 0; n < NF; n++) {
            int col = n0 + wc * 64 + n * 16 + lrow;
            float bv = bias[col];
#pragma unroll
            for (int j = 0; j < 4; j++) {
                int row = rbase + j;
                float v = acc[m][n][j] + bv;
                size_t off = (size_t)row * N + col;
                if constexpr (MODE == 0) {
                    ((u16*)outp)[off] = f2b(v);
                } else if constexpr (MODE == 1) {
                    ((float*)outp)[off] = v + resid[off];
                } else {
                    float gl = 0.5f * v * (1.0f + erf_inl(v * 0.70710678118654752f));
                    ((u16*)outp)[off] = f2b(gl);
                }
            }
        }
    }
}

// ---- V transpose: qkv[B*T, 3072] v-part -> vt[B,H,64,T] ----
__global__ __launch_bounds__(256) void vtrans_kernel(const u16* __restrict__ qkv,
                                                     u16* __restrict__ vt) {
    __shared__ u16 tile[32][66];
    int bh = blockIdx.y, b = bh >> 4, h = bh & 15;
    int t0 = blockIdx.x * 32;
    int dx = threadIdx.x & 63, ty = threadIdx.x >> 6;
    for (int i = 0; i < 8; i++) {
        int tt = ty * 8 + i;
        tile[tt][dx] = qkv[(size_t)(b * T_ + t0 + tt) * 3072 + 2048 + h * 64 + dx];
    }
    __syncthreads();
    int tx = threadIdx.x & 31, dy = threadIdx.x >> 5;
    for (int i = 0; i < 8; i++) {
        int d = dy * 8 + i;
        vt[((size_t)bh * 64 + d) * T_ + t0 + tx] = tile[tx][d];
    }
}

// ---- flash attention: 8 waves x 16 q-rows (QBLK=128), 64-key LDS tiles,
// double-buffered K/V stage + mask prefetched one tile ahead into registers.
__global__ __launch_bounds__(512, 4) void attn_kernel(const u16* __restrict__ qkv,
                                                      const u16* __restrict__ vt,
                                                      const float* __restrict__ mask,
                                                      u16* __restrict__ obuf) {
    __shared__ u16 Ks[2][4096];
    __shared__ u16 Vs[2][4096];
    __shared__ u16 Ps[8][1024];
    int qt = blockIdx.x, bh = blockIdx.y, b = bh >> 4, h = bh & 15;
    int tid = threadIdx.x, w = tid >> 6, l = tid & 63;
    int lrow = l & 15, lgrp = l >> 4;

    int qrow = qt * 128 + w * 16 + lrow;
    int qrc = qrow < T_ ? qrow : T_ - 1;
    const u16* qp = qkv + (size_t)(b * T_ + qrc) * 3072 + h * 64 + lgrp * 8;
    short8 aq0, aq1;
    {
        short8 r0 = *(const short8*)qp;
        short8 r1 = *(const short8*)(qp + 32);
        for (int i = 0; i < 8; i++) {
            aq0[i] = (short)f2b(b2f((u16)r0[i]) * 0.125f);
            aq1[i] = (short)f2b(b2f((u16)r1[i]) * 0.125f);
        }
    }

    int tq0 = qt * 128 + w * 16 + lgrp * 4;
    bool qvalid = tq0 < T_;
    const float* mrowp[4];
#pragma unroll
    for (int j = 0; j < 4; j++) {
        int tq = tq0 + j; if (tq >= T_) tq = T_ - 1;
        mrowp[j] = mask + (size_t)tq * T_;
    }

    float m_r[4], l_r[4];
    f32x4 oacc[4];
    for (int j = 0; j < 4; j++) { m_r[j] = -1e30f; l_r[j] = 0.f; }
    for (int n = 0; n < 4; n++) oacc[n] = (f32x4){0, 0, 0, 0};

    int srow = tid >> 3, sp = tid & 7;
    int se = (sp ^ (srow & 7)) * 8;
    const u16* kbase = qkv + (size_t)b * T_ * 3072 + 1024 + h * 64;
    const u16* vbase = vt + (size_t)bh * 64 * T_;

#define STAGE_KV(buf, kk0)                                                        \
    do {                                                                          \
        gload_lds16(kbase + (size_t)((kk0) + srow) * 3072 + se, &Ks[buf][w * 512]); \
        gload_lds16(vbase + (size_t)srow * T_ + (kk0) + se, &Vs[buf][w * 512]);     \
    } while (0)

    float mc[16], mn[16];
    STAGE_KV(0, 0);
#pragma unroll
    for (int j = 0; j < 4; j++)
#pragma unroll
        for (int c = 0; c < 4; c++)
            mc[j * 4 + c] = mrowp[j][c * 16 + lrow];
    __syncthreads();

    int cur = 0;
    u16* Pw = Ps[w];
    int swl = lrow & 7;
    int slot0 = (lgrp ^ swl) * 8, slot1 = ((lgrp + 4) ^ swl) * 8;

    for (int kt = 0; kt < 13; ++kt) {
        int kk0 = kt * 64;
        if (kt < 12) {
            STAGE_KV(cur ^ 1, kk0 + 64);
#pragma unroll
            for (int j = 0; j < 4; j++)
#pragma unroll
                for (int c = 0; c < 4; c++)
                    mn[j * 4 + c] = mrowp[j][kk0 + 64 + c * 16 + lrow];
        }

        f32x4 sc[4];
        for (int c = 0; c < 4; c++) sc[c] = (f32x4){0, 0, 0, 0};
        const u16* Kb = Ks[cur];
        __builtin_amdgcn_s_setprio(1);
        for (int c = 0; c < 4; c++) {
            const u16* krow = Kb + (c * 16 + lrow) * 64;
            short8 bk0 = *(const short8*)(krow + slot0);
            short8 bk1 = *(const short8*)(krow + slot1);
            sc[c] = __builtin_amdgcn_mfma_f32_16x16x32_bf16(aq0, bk0, sc[c], 0, 0, 0);
            sc[c] = __builtin_amdgcn_mfma_f32_16x16x32_bf16(aq1, bk1, sc[c], 0, 0, 0);
        }
        __builtin_amdgcn_s_setprio(0);

        int lo3 = lrow & 7, hi = lrow >> 3;
#pragma unroll
        for (int j = 0; j < 4; j++) {
            float s0 = sc[0][j] + mc[j * 4 + 0];
            float s1 = sc[1][j] + mc[j * 4 + 1];
            float s2 = sc[2][j] + mc[j * 4 + 2];
            float s3 = sc[3][j] + mc[j * 4 + 3];
            float mx = fmaxf(fmaxf(s0, s1), fmaxf(s2, s3));
            mx = fmaxf(mx, __shfl_xor(mx, 1));
            mx = fmaxf(mx, __shfl_xor(mx, 2));
            mx = fmaxf(mx, __shfl_xor(mx, 4));
            mx = fmaxf(mx, __shfl_xor(mx, 8));
            float mnew = fmaxf(m_r[j], mx);
            float scf = __expf(m_r[j] - mnew);
            float p0 = __expf(s0 - mnew), p1 = __expf(s1 - mnew);
            float p2 = __expf(s2 - mnew), p3 = __expf(s3 - mnew);
            float ps = (p0 + p1) + (p2 + p3);
            ps += __shfl_xor(ps, 1); ps += __shfl_xor(ps, 2);
            ps += __shfl_xor(ps, 4); ps += __shfl_xor(ps, 8);
            l_r[j] = l_r[j] * scf + ps;
            m_r[j] = mnew;
            for (int n = 0; n < 4; n++) oacc[n][j] *= scf;
            int row_p = lgrp * 4 + j, swp = row_p & 7;
            u16* pr = Pw + row_p * 64;
            pr[((hi ^ swp) * 8) + lo3]       = f2b(p0);
            pr[(((2 + hi) ^ swp) * 8) + lo3] = f2b(p1);
            pr[(((4 + hi) ^ swp) * 8) + lo3] = f2b(p2);
            pr[(((6 + hi) ^ swp) * 8) + lo3] = f2b(p3);
        }

        short8 ap0 = *(const short8*)&Pw[lrow * 64 + slot0];
        short8 ap1 = *(const short8*)&Pw[lrow * 64 + slot1];
        const u16* Vb = Vs[cur];
        __builtin_amdgcn_s_setprio(1);
        for (int n = 0; n < 4; n++) {
            const u16* vrow = Vb + (n * 16 + lrow) * 64;
            short8 bv0 = *(const short8*)(vrow + slot0);
            short8 bv1 = *(const short8*)(vrow + slot1);
            oacc[n] = __builtin_amdgcn_mfma_f32_16x16x32_bf16(ap0, bv0, oacc[n], 0, 0, 0);
            oacc[n] = __builtin_amdgcn_mfma_f32_16x16x32_bf16(ap1, bv1, oacc[n], 0, 0, 0);
        }
        __builtin_amdgcn_s_setprio(0);

        __syncthreads();
#pragma unroll
        for (int i = 0; i < 16; i++) mc[i] = mn[i];
        cur ^= 1;
    }
#undef STAGE_KV

    if (qvalid) {
        for (int j = 0; j < 4; j++) {
            float inv = 1.0f / l_r[j];
            int t = tq0 + j;
            for (int n = 0; n < 4; n++)
                obuf[(size_t)(b * T_ + t) * 1024 + h * 64 + n * 16 + lrow] = f2b(oacc[n][j] * inv);
        }
    }
}

// ---- LoRA: per (b, group of 16 tokens) add (z @ A_e @ B_e)/R into out ----
__global__ __launch_bounds__(256) void lora_kernel(const u16* __restrict__ snorm,
                                                   const float* __restrict__ lA,
                                                   const float* __restrict__ lB,
                                                   const int* __restrict__ idx,
                                                   float* __restrict__ outp) {
    __shared__ float down[16][8];
    int blk = blockIdx.x, b = blk >> 4, kk = blk & 15;
    int e = idx[kk];
    int tok0 = b * T_ + NB_ + kk * 16;
    int tid = threadIdx.x;
    {
        int m = tid >> 4;            // 0..15
        int r = (tid >> 1) & 7;      // 0..7
        int dh = tid & 1;            // 0..1
        const u16* z = snorm + (size_t)(tok0 + m) * D_ + dh * 512;
        const float* Ae = lA + (size_t)e * D_ * 8 + (size_t)(dh * 512) * 8 + r;
        float acc = 0.f;
        for (int d = 0; d < 512; ++d) acc += b2f(z[d]) * Ae[(size_t)d * 8];
        acc += __shfl_xor(acc, 1);
        if (dh == 0) down[m][r] = acc;
    }
    __syncthreads();
    for (int ci = 0; ci < 4; ci++) {
        int col = tid + ci * 256;
        float br[8];
        for (int r = 0; r < 8; r++) br[r] = lB[((size_t)e * 8 + r) * D_ + col];
        for (int m = 0; m < 16; m++) {
            float acc = 0.f;
            for (int r = 0; r < 8; r++) acc += down[m][r] * br[r];
            outp[(size_t)(tok0 + m) * D_ + col] += acc * 0.125f;
        }
    }
}

extern "C" void kernel_launch(void* const* d_in, const int* in_sizes, int n_in,
                              void* d_out, int out_size, void* d_ws, size_t ws_size,
                              hipStream_t stream) {
    const float* s      = (const float*)d_in[0];
    const float* mask   = (const float*)d_in[1];
    const float* g1     = (const float*)d_in[2];
    const float* b1     = (const float*)d_in[3];
    const float* w_qkv  = (const float*)d_in[4];
    const float* b_qkv  = (const float*)d_in[5];
    const float* w_proj = (const float*)d_in[6];
    const float* b_proj = (const float*)d_in[7];
    const float* g2     = (const float*)d_in[8];
    const float* b2     = (const float*)d_in[9];
    const float* w_fc1  = (const float*)d_in[10];
    const float* b_fc1  = (const float*)d_in[11];
    const float* w_fc2  = (const float*)d_in[12];
    const float* b_fc2  = (const float*)d_in[13];
    const float* lA     = (const float*)d_in[14];
    const float* lB     = (const float*)d_in[15];
    const int*   eidx   = (const int*)d_in[16];
    float* out = (float*)d_out;
    char* ws = (char*)d_ws;

    // workspace layout (max 115 MB, lifetime-based reuse)
    u16*   wqkvT = (u16*)(ws + 0);            // 6.0 MB
    u16*   wprojT= (u16*)(ws + 6291456);      // 2.0 MB
    u16*   wfc1T = (u16*)(ws + 8388608);      // 8.0 MB
    u16*   wfc2T = (u16*)(ws + 16777216);     // 8.0 MB
    float* s1    = (float*)(ws + 25165824);   // 26 MB f32, ends 50 MB
    u16*   xln   = (u16*)(ws + 52428800);     // 13 MB (x_ln -> o -> s_norm)
    u16*   vt    = (u16*)(ws + 66060288);     // 13 MB (v_t; dead after attn)
    u16*   qkv   = (u16*)(ws + 79691776);     // 39 MB (qkv; dead after attn)
    u16*   h     = (u16*)(ws + 66060288);     // 54.5 MB (overwrites vt+qkv), ends ~115 MB

    wtrans_all<<<12288, 256, 0, stream>>>(w_qkv, w_proj, w_fc1, w_fc2,
                                          wqkvT, wprojT, wfc1T, wfc2T);
    ln_kernel<<<NT_, 256, 0, stream>>>(s, g1, b1, xln);
    gemm5<0><<<dim3(3072 / 256, NT_ / 256), 512, 0, stream>>>(xln, wqkvT, b_qkv, qkv, NT_, 3072, 1024);
    vtrans_kernel<<<dim3(26, 128), 256, 0, stream>>>(qkv, vt);
    attn_kernel<<<dim3(7, 128), 512, 0, stream>>>(qkv, vt, mask, xln);
    gemm3<128, 128, 2, 2, 1><<<dim3(1024 / 128, NT_ / 128), 256, 0, stream>>>(xln, wprojT, b_proj, s, s1, NT_, 1024, 1024);
    ln_kernel<<<NT_, 256, 0, stream>>>(s1, g2, b2, xln);
    gemm5<2><<<dim3(4096 / 256, NT_ / 256), 512, 0, stream>>>(xln, wfc1T, b_fc1, h, NT_, 4096, 1024);
    gemm3<128, 128, 2, 2, 1><<<dim3(1024 / 128, NT_ / 128), 256, 0, stream>>>(h, wfc2T, b_fc2, s1, out, NT_, 1024, 4096);
    lora_kernel<<<128, 256, 0, stream>>>(xln, lA, lB, eidx, out);
}

// Round 16
// 402.204 us; speedup vs baseline: 1.0885x; 1.0081x over previous
//
#include <hip/hip_runtime.h>
#include <hip/hip_bf16.h>
#include <math.h>

typedef unsigned short u16;
typedef __attribute__((ext_vector_type(8))) short short8;
typedef __attribute__((ext_vector_type(4))) float f32x4;

constexpr int B_ = 8, T_ = 832, D_ = 1024, H_ = 16, HID_ = 4096, NB_ = 576;
constexpr int NT_ = B_ * T_;   // 6656 tokens

// ---- bf16 bit helpers (RNE) ----
__device__ inline u16 f2b(float f) {
    union { float f; unsigned u; } x{f};
    unsigned r = (x.u + 0x7FFFu + ((x.u >> 16) & 1u)) >> 16;
    return (u16)r;
}
__device__ inline float b2f(u16 b) {
    union { unsigned u; float f; } x; x.u = ((unsigned)b) << 16; return x.f;
}

// inline erf (Abramowitz-Stegun 7.1.26, |err| < 1.5e-7), no libcall
__device__ inline float erf_inl(float x) {
    float ax = fabsf(x);
    float t = __frcp_rn(1.0f + 0.3275911f * ax);
    float p = 1.061405429f;
    p = p * t - 1.453152027f;
    p = p * t + 1.421413741f;
    p = p * t - 0.284496736f;
    p = p * t + 0.254829592f;
    p = p * t;
    float e = 1.0f - p * __expf(-ax * ax);
    return copysignf(e, x);
}

__device__ inline void gload_lds16(const void* g, void* l) {
    __builtin_amdgcn_global_load_lds((const __attribute__((address_space(1))) void*)g,
                                     (__attribute__((address_space(3))) void*)l, 16, 0, 0);
}

// ---- merged weight transpose: all four weights, flat grid ----
__global__ __launch_bounds__(256) void wtrans_all(const float* __restrict__ wq,
                                                  const float* __restrict__ wp,
                                                  const float* __restrict__ w1,
                                                  const float* __restrict__ w2,
                                                  u16* __restrict__ oq, u16* __restrict__ op,
                                                  u16* __restrict__ o1, u16* __restrict__ o2) {
    __shared__ u16 tile[32][34];
    int bid = blockIdx.x;
    const float* in; u16* out; int K, N, idx;
    if (bid < 3072)      { in = wq; out = oq; K = 1024; N = 3072; idx = bid; }
    else if (bid < 4096) { in = wp; out = op; K = 1024; N = 1024; idx = bid - 3072; }
    else if (bid < 8192) { in = w1; out = o1; K = 1024; N = 4096; idx = bid - 4096; }
    else                 { in = w2; out = o2; K = 4096; N = 1024; idx = bid - 8192; }
    int nx = N >> 5;
    int n0 = (idx % nx) * 32, k0 = (idx / nx) * 32;
    int tx = threadIdx.x & 31, ty = threadIdx.x >> 5;
    for (int i = 0; i < 4; i++) {
        int k = k0 + ty + i * 8;
        tile[ty + i * 8][tx] = f2b(in[(size_t)k * N + n0 + tx]);
    }
    __syncthreads();
    for (int i = 0; i < 4; i++) {
        int n = n0 + ty + i * 8;
        out[(size_t)n * K + k0 + tx] = tile[tx][ty + i * 8];
    }
}

// ---- LayerNorm: f32 in -> bf16 out, one block per row (D=1024, 256 thr) ----
__global__ __launch_bounds__(256) void ln_kernel(const float* __restrict__ x,
                                                 const float* __restrict__ g,
                                                 const float* __restrict__ bt,
                                                 u16* __restrict__ out) {
    int row = blockIdx.x, tid = threadIdx.x;
    float4 v = ((const float4*)(x + (size_t)row * D_))[tid];
    float s = v.x + v.y + v.z + v.w;
    float q = v.x * v.x + v.y * v.y + v.z * v.z + v.w * v.w;
    for (int o = 1; o < 64; o <<= 1) { s += __shfl_xor(s, o); q += __shfl_xor(q, o); }
    __shared__ float red[4][2];
    if ((tid & 63) == 0) { red[tid >> 6][0] = s; red[tid >> 6][1] = q; }
    __syncthreads();
    s = red[0][0] + red[1][0] + red[2][0] + red[3][0];
    q = red[0][1] + red[1][1] + red[2][1] + red[3][1];
    float mean = s * (1.0f / D_);
    float var = q * (1.0f / D_) - mean * mean;
    float inv = rsqrtf(fmaxf(var, 0.f) + 1e-6f);
    float4 gv = ((const float4*)g)[tid];
    float4 bv = ((const float4*)bt)[tid];
    u16* orow = out + (size_t)row * D_ + tid * 4;
    orow[0] = f2b((v.x - mean) * inv * gv.x + bv.x);
    orow[1] = f2b((v.y - mean) * inv * gv.y + bv.y);
    orow[2] = f2b((v.z - mean) * inv * gv.z + bv.z);
    orow[3] = f2b((v.w - mean) * inv * gv.w + bv.w);
}

// ---- gemm5: 256x256 tile, BK=64, 8 waves (2M x 4N), per-wave 128x64 output.
// Double-buffered 128KB LDS; one vmcnt(0)+s_barrier per K-tile.
// Row = 128B: slot^=(row&7) 16B-granule swizzle (HW-verified 0-conflict),
// applied as inverse on the global stage source (LDS dest stays linear).
// MODE 0: bf16 out. MODE 2: exact GELU, bf16 out.
template<int MODE>
__global__ __launch_bounds__(512, 2)
void gemm5(const u16* __restrict__ A, const u16* __restrict__ Bt,
           const float* __restrict__ bias, void* __restrict__ outp,
           int M, int N, int K) {
    __shared__ u16 lds5[2][32768];   // [buf][A 16384 | B 16384] u16
    int tid = threadIdx.x, l = tid & 63, w = tid >> 6;
    int lrow = l & 15, lgrp = l >> 4;
    int wr = w >> 2, wc = w & 3;

    // XCD-aware bijective block swizzle (grids are multiples of 8)
    int nwg = gridDim.x * gridDim.y;
    int bid = blockIdx.y * gridDim.x + blockIdx.x;
    int cpx = nwg >> 3;
    int swz = (bid & 7) * cpx + (bid >> 3);
    int bx = swz % gridDim.x, by = swz / gridDim.x;
    int m0 = by * 256, n0 = bx * 256;

    // stage: 4096 chunks of 16B per K-tile (A: c<2048, B: c>=2048), 8/thread.
    const u16* src[8];
    int ldst[8];
#pragma unroll
    for (int i = 0; i < 8; i++) {
        int c = i * 512 + tid;
        int row = (c & 2047) >> 3;
        int ls = (c & 7) ^ (row & 7);
        src[i] = (c < 2048 ? A + (size_t)(m0 + row) * K : Bt + (size_t)(n0 + row) * K) + ls * 8;
        ldst[i] = c * 8;   // linear LDS dest (wave-uniform base + lane*16B)
    }

#define STAGE5(bufi, t)                                                      \
    do {                                                                     \
        int ko = (t) * 64;                                                   \
        u16* bb = &lds5[bufi][0];                                            \
        _Pragma("unroll")                                                    \
        for (int i = 0; i < 8; i++) gload_lds16(src[i] + ko, bb + ldst[i]);  \
    } while (0)

    f32x4 acc[8][4];
#pragma unroll
    for (int m = 0; m < 8; m++)
#pragma unroll
        for (int n = 0; n < 4; n++) acc[m][n] = (f32x4){0, 0, 0, 0};

    int sw = lrow & 7;
    int slot0 = (lgrp ^ sw) * 8, slot1 = ((4 + lgrp) ^ sw) * 8;
    int arow[8], brow[4];
#pragma unroll
    for (int m = 0; m < 8; m++) arow[m] = (wr * 128 + m * 16 + lrow) * 64;
#pragma unroll
    for (int n = 0; n < 4; n++) brow[n] = 16384 + (wc * 64 + n * 16 + lrow) * 64;

    int nkt = K >> 6;
    STAGE5(0, 0);
    asm volatile("s_waitcnt vmcnt(0)" ::: "memory");
    asm volatile("s_barrier" ::: "memory");

    for (int t = 0; t < nkt; ++t) {
        int ct = t & 1;
        if (t + 1 < nkt) STAGE5(ct ^ 1, t + 1);
        const u16* bp = &lds5[ct][0];
#pragma unroll
        for (int kh = 0; kh < 2; kh++) {
            int so = kh ? slot1 : slot0;
            short8 bf[4];
#pragma unroll
            for (int n = 0; n < 4; n++) bf[n] = *(const short8*)(bp + brow[n] + so);
#pragma unroll
            for (int mg = 0; mg < 2; mg++) {
                short8 af[4];
#pragma unroll
                for (int mi = 0; mi < 4; mi++) af[mi] = *(const short8*)(bp + arow[mg * 4 + mi] + so);
#pragma unroll
                for (int mi = 0; mi < 4; mi++)
#pragma unroll
                    for (int n = 0; n < 4; n++)
                        acc[mg * 4 + mi][n] =
                            __builtin_amdgcn_mfma_f32_16x16x32_bf16(af[mi], bf[n], acc[mg * 4 + mi][n], 0, 0, 0);
            }
        }
        if (t + 1 < nkt) asm volatile("s_waitcnt vmcnt(0)" ::: "memory");
        asm volatile("s_barrier" ::: "memory");
    }
#undef STAGE5

#pragma unroll
    for (int m = 0; m < 8; m++) {
        int rb = m0 + wr * 128 + m * 16 + lgrp * 4;
#pragma unroll
        for (int n = 0; n < 4; n++) {
            int col = n0 + wc * 64 + n * 16 + lrow;
            float bv = bias[col];
#pragma unroll
            for (int j = 0; j < 4; j++) {
                float v = acc[m][n][j] + bv;
                size_t off = (size_t)(rb + j) * N + col;
                if constexpr (MODE == 0) {
                    ((u16*)outp)[off] = f2b(v);
                } else {
                    float gl = 0.5f * v * (1.0f + erf_inl(v * 0.70710678118654752f));
                    ((u16*)outp)[off] = f2b(gl);
                }
            }
        }
    }
}

// ---- Pipelined GEMM (128-tiles): triple-buffered, depth-2 prefetch ----
template<int BM, int BN, int WR, int WC, int MODE>
__global__ __launch_bounds__(WR * WC * 64, (WR * WC == 8) ? 2 : 3)
void gemm3(const u16* __restrict__ A, const u16* __restrict__ Bt,
           const float* __restrict__ bias, const float* __restrict__ resid,
           void* __restrict__ outp, int M, int N, int K) {
    constexpr int THREADS = WR * WC * 64;
    constexpr int MF = BM / WR / 16;
    constexpr int NF = BN / WC / 16;
    constexpr int NROWS = BM + BN;
    constexpr int CHUNKS = NROWS * 4 / THREADS;
    constexpr int LDSU = NROWS * 32;
    __shared__ u16 lds_[3 * LDSU];

    int tid = threadIdx.x, l = tid & 63, w = tid >> 6;
    int lrow = l & 15, lgrp = l >> 4;
    int wr = w / WC, wc = w % WC;

    int nwg = gridDim.x * gridDim.y;
    int bid = blockIdx.y * gridDim.x + blockIdx.x;
    int cpx = nwg >> 3;
    int swz = (bid & 7) * cpx + (bid >> 3);
    int bx = swz % gridDim.x, by = swz / gridDim.x;
    int m0 = by * BM, n0 = bx * BN;

    const u16* src[CHUNKS];
    int ldst[CHUNKS];
#pragma unroll
    for (int i = 0; i < CHUNKS; i++) {
        int c = i * THREADS + tid;
        int lc = (c & ~7) | ((c ^ (c >> 3)) & 7);
        int row = lc >> 2, colu = (lc & 3) * 8;
        src[i] = (row < BM) ? A + (size_t)(m0 + row) * K + colu
                            : Bt + (size_t)(n0 + row - BM) * K + colu;
        ldst[i] = c * 8;
    }

#define STAGE3(bufi, kt)                                                    \
    do {                                                                    \
        int kof = (kt) * 32;                                                \
        u16* bb = lds_ + (bufi) * LDSU;                                     \
        _Pragma("unroll")                                                   \
        for (int i = 0; i < CHUNKS; i++) gload_lds16(src[i] + kof, bb + ldst[i]); \
    } while (0)

    f32x4 acc[MF][NF];
#pragma unroll
    for (int m = 0; m < MF; m++)
#pragma unroll
        for (int n = 0; n < NF; n++) acc[m][n] = (f32x4){0, 0, 0, 0};

    int aidx[MF], bidx[NF];
#pragma unroll
    for (int m = 0; m < MF; m++) {
        int row = wr * 64 + m * 16 + lrow;
        aidx[m] = (row * 32 + lgrp * 8) ^ (((row >> 1) & 7) << 3);
    }
#pragma unroll
    for (int n = 0; n < NF; n++) {
        int row = BM + wc * 64 + n * 16 + lrow;
        bidx[n] = (row * 32 + lgrp * 8) ^ (((row >> 1) & 7) << 3);
    }

    int nkt = K >> 5;
    STAGE3(0, 0);
    STAGE3(1, 1);
    if constexpr (CHUNKS == 3) asm volatile("s_waitcnt vmcnt(3)" ::: "memory");
    else                       asm volatile("s_waitcnt vmcnt(4)" ::: "memory");
    asm volatile("s_barrier" ::: "memory");

    int cur = 0;
    for (int t = 0; t < nkt; ++t) {
        int sb = cur + 2; if (sb >= 3) sb -= 3;
        if (t + 2 < nkt) STAGE3(sb, t + 2);

        const u16* bp = lds_ + cur * LDSU;
        short8 af[MF], bfr[NF];
#pragma unroll
        for (int m = 0; m < MF; m++) af[m] = *(const short8*)(bp + aidx[m]);
#pragma unroll
        for (int n = 0; n < NF; n++) bfr[n] = *(const short8*)(bp + bidx[n]);

        __builtin_amdgcn_s_setprio(1);
#pragma unroll
        for (int m = 0; m < MF; m++)
#pragma unroll
            for (int n = 0; n < NF; n++)
                acc[m][n] = __builtin_amdgcn_mfma_f32_16x16x32_bf16(af[m], bfr[n], acc[m][n], 0, 0, 0);
        __builtin_amdgcn_s_setprio(0);

        if (t + 2 < nkt) {
            if constexpr (CHUNKS == 3) asm volatile("s_waitcnt vmcnt(3)" ::: "memory");
            else                       asm volatile("s_waitcnt vmcnt(4)" ::: "memory");
        } else if (t + 1 < nkt) {
            asm volatile("s_waitcnt vmcnt(0)" ::: "memory");
        }
        asm volatile("s_barrier" ::: "memory");
        cur = cur + 1; if (cur == 3) cur = 0;
    }
#undef STAGE3

#pragma unroll
    for (int m = 0; m < MF; m++) {
        int rbase = m0 + wr * 64 + m * 16 + lgrp * 4;
#pragma unroll
        for (int n = 0; n < NF; n++) {
            int col = n0 + wc * 64 + n * 16 + lrow;
            float bv = bias[col];
#pragma unroll
            for (int j = 0; j < 4; j++) {
                int row = rbase + j;
                float v = acc[m][n][j] + bv;
                size_t off = (size_t)row * N + col;
                if constexpr (MODE == 0) {
                    ((u16*)outp)[off] = f2b(v);
                } else if constexpr (MODE == 1) {
                    ((float*)outp)[off] = v + resid[off];
                } else {
                    float gl = 0.5f * v * (1.0f + erf_inl(v * 0.70710678118654752f));
                    ((u16*)outp)[off] = f2b(gl);
                }
            }
        }
    }
}

// ---- V transpose: qkv[B*T, 3072] v-part -> vt[B,H,64,T] ----
__global__ __launch_bounds__(256) void vtrans_kernel(const u16* __restrict__ qkv,
                                                     u16* __restrict__ vt) {
    __shared__ u16 tile[32][66];
    int bh = blockIdx.y, b = bh >> 4, h = bh & 15;
    int t0 = blockIdx.x * 32;
    int dx = threadIdx.x & 63, ty = threadIdx.x >> 6;
    for (int i = 0; i < 8; i++) {
        int tt = ty * 8 + i;
        tile[tt][dx] = qkv[(size_t)(b * T_ + t0 + tt) * 3072 + 2048 + h * 64 + dx];
    }
    __syncthreads();
    int tx = threadIdx.x & 31, dy = threadIdx.x >> 5;
    for (int i = 0; i < 8; i++) {
        int d = dy * 8 + i;
        vt[((size_t)bh * 64 + d) * T_ + t0 + tx] = tile[tx][d];
    }
}

// ---- flash attention: 8 waves x 16 q-rows (QBLK=128), 64-key LDS tiles,
// double-buffered K/V stage + mask prefetched one tile ahead into registers.
__global__ __launch_bounds__(512, 4) void attn_kernel(const u16* __restrict__ qkv,
                                                      const u16* __restrict__ vt,
                                                      const float* __restrict__ mask,
                                                      u16* __restrict__ obuf) {
    __shared__ u16 Ks[2][4096];
    __shared__ u16 Vs[2][4096];
    __shared__ u16 Ps[8][1024];
    int qt = blockIdx.x, bh = blockIdx.y, b = bh >> 4, h = bh & 15;
    int tid = threadIdx.x, w = tid >> 6, l = tid & 63;
    int lrow = l & 15, lgrp = l >> 4;

    int qrow = qt * 128 + w * 16 + lrow;
    int qrc = qrow < T_ ? qrow : T_ - 1;
    const u16* qp = qkv + (size_t)(b * T_ + qrc) * 3072 + h * 64 + lgrp * 8;
    short8 aq0, aq1;
    {
        short8 r0 = *(const short8*)qp;
        short8 r1 = *(const short8*)(qp + 32);
        for (int i = 0; i < 8; i++) {
            aq0[i] = (short)f2b(b2f((u16)r0[i]) * 0.125f);
            aq1[i] = (short)f2b(b2f((u16)r1[i]) * 0.125f);
        }
    }

    int tq0 = qt * 128 + w * 16 + lgrp * 4;
    bool qvalid = tq0 < T_;
    const float* mrowp[4];
#pragma unroll
    for (int j = 0; j < 4; j++) {
        int tq = tq0 + j; if (tq >= T_) tq = T_ - 1;
        mrowp[j] = mask + (size_t)tq * T_;
    }

    float m_r[4], l_r[4];
    f32x4 oacc[4];
    for (int j = 0; j < 4; j++) { m_r[j] = -1e30f; l_r[j] = 0.f; }
    for (int n = 0; n < 4; n++) oacc[n] = (f32x4){0, 0, 0, 0};

    int srow = tid >> 3, sp = tid & 7;
    int se = (sp ^ (srow & 7)) * 8;
    const u16* kbase = qkv + (size_t)b * T_ * 3072 + 1024 + h * 64;
    const u16* vbase = vt + (size_t)bh * 64 * T_;

#define STAGE_KV(buf, kk0)                                                        \
    do {                                                                          \
        gload_lds16(kbase + (size_t)((kk0) + srow) * 3072 + se, &Ks[buf][w * 512]); \
        gload_lds16(vbase + (size_t)srow * T_ + (kk0) + se, &Vs[buf][w * 512]);     \
    } while (0)

    float mc[16], mn[16];
    STAGE_KV(0, 0);
#pragma unroll
    for (int j = 0; j < 4; j++)
#pragma unroll
        for (int c = 0; c < 4; c++)
            mc[j * 4 + c] = mrowp[j][c * 16 + lrow];
    __syncthreads();

    int cur = 0;
    u16* Pw = Ps[w];
    int swl = lrow & 7;
    int slot0 = (lgrp ^ swl) * 8, slot1 = ((lgrp + 4) ^ swl) * 8;

    for (int kt = 0; kt < 13; ++kt) {
        int kk0 = kt * 64;
        if (kt < 12) {
            STAGE_KV(cur ^ 1, kk0 + 64);
#pragma unroll
            for (int j = 0; j < 4; j++)
#pragma unroll
                for (int c = 0; c < 4; c++)
                    mn[j * 4 + c] = mrowp[j][kk0 + 64 + c * 16 + lrow];
        }

        f32x4 sc[4];
        for (int c = 0; c < 4; c++) sc[c] = (f32x4){0, 0, 0, 0};
        const u16* Kb = Ks[cur];
        __builtin_amdgcn_s_setprio(1);
        for (int c = 0; c < 4; c++) {
            const u16* krow = Kb + (c * 16 + lrow) * 64;
            short8 bk0 = *(const short8*)(krow + slot0);
            short8 bk1 = *(const short8*)(krow + slot1);
            sc[c] = __builtin_amdgcn_mfma_f32_16x16x32_bf16(aq0, bk0, sc[c], 0, 0, 0);
            sc[c] = __builtin_amdgcn_mfma_f32_16x16x32_bf16(aq1, bk1, sc[c], 0, 0, 0);
        }
        __builtin_amdgcn_s_setprio(0);

        int lo3 = lrow & 7, hi = lrow >> 3;
#pragma unroll
        for (int j = 0; j < 4; j++) {
            float s0 = sc[0][j] + mc[j * 4 + 0];
            float s1 = sc[1][j] + mc[j * 4 + 1];
            float s2 = sc[2][j] + mc[j * 4 + 2];
            float s3 = sc[3][j] + mc[j * 4 + 3];
            float mx = fmaxf(fmaxf(s0, s1), fmaxf(s2, s3));
            mx = fmaxf(mx, __shfl_xor(mx, 1));
            mx = fmaxf(mx, __shfl_xor(mx, 2));
            mx = fmaxf(mx, __shfl_xor(mx, 4));
            mx = fmaxf(mx, __shfl_xor(mx, 8));
            float mnew = fmaxf(m_r[j], mx);
            float scf = __expf(m_r[j] - mnew);
            float p0 = __expf(s0 - mnew), p1 = __expf(s1 - mnew);
            float p2 = __expf(s2 - mnew), p3 = __expf(s3 - mnew);
            float ps = (p0 + p1) + (p2 + p3);
            ps += __shfl_xor(ps, 1); ps += __shfl_xor(ps, 2);
            ps += __shfl_xor(ps, 4); ps += __shfl_xor(ps, 8);
            l_r[j] = l_r[j] * scf + ps;
            m_r[j] = mnew;
            for (int n = 0; n < 4; n++) oacc[n][j] *= scf;
            int row_p = lgrp * 4 + j, swp = row_p & 7;
            u16* pr = Pw + row_p * 64;
            pr[((hi ^ swp) * 8) + lo3]       = f2b(p0);
            pr[(((2 + hi) ^ swp) * 8) + lo3] = f2b(p1);
            pr[(((4 + hi) ^ swp) * 8) + lo3] = f2b(p2);
            pr[(((6 + hi) ^ swp) * 8) + lo3] = f2b(p3);
        }

        short8 ap0 = *(const short8*)&Pw[lrow * 64 + slot0];
        short8 ap1 = *(const short8*)&Pw[lrow * 64 + slot1];
        const u16* Vb = Vs[cur];
        __builtin_amdgcn_s_setprio(1);
        for (int n = 0; n < 4; n++) {
            const u16* vrow = Vb + (n * 16 + lrow) * 64;
            short8 bv0 = *(const short8*)(vrow + slot0);
            short8 bv1 = *(const short8*)(vrow + slot1);
            oacc[n] = __builtin_amdgcn_mfma_f32_16x16x32_bf16(ap0, bv0, oacc[n], 0, 0, 0);
            oacc[n] = __builtin_amdgcn_mfma_f32_16x16x32_bf16(ap1, bv1, oacc[n], 0, 0, 0);
        }
        __builtin_amdgcn_s_setprio(0);

        __syncthreads();
#pragma unroll
        for (int i = 0; i < 16; i++) mc[i] = mn[i];
        cur ^= 1;
    }
#undef STAGE_KV

    if (qvalid) {
        for (int j = 0; j < 4; j++) {
            float inv = 1.0f / l_r[j];
            int t = tq0 + j;
            for (int n = 0; n < 4; n++)
                obuf[(size_t)(b * T_ + t) * 1024 + h * 64 + n * 16 + lrow] = f2b(oacc[n][j] * inv);
        }
    }
}

// ---- LoRA: per (b, group of 16 tokens) add (z @ A_e @ B_e)/R into out ----
__global__ __launch_bounds__(256) void lora_kernel(const u16* __restrict__ snorm,
                                                   const float* __restrict__ lA,
                                                   const float* __restrict__ lB,
                                                   const int* __restrict__ idx,
                                                   float* __restrict__ outp) {
    __shared__ float down[16][8];
    int blk = blockIdx.x, b = blk >> 4, kk = blk & 15;
    int e = idx[kk];
    int tok0 = b * T_ + NB_ + kk * 16;
    int tid = threadIdx.x;
    {
        int m = tid >> 4;            // 0..15
        int r = (tid >> 1) & 7;      // 0..7
        int dh = tid & 1;            // 0..1
        const u16* z = snorm + (size_t)(tok0 + m) * D_ + dh * 512;
        const float* Ae = lA + (size_t)e * D_ * 8 + (size_t)(dh * 512) * 8 + r;
        float acc = 0.f;
        for (int d = 0; d < 512; ++d) acc += b2f(z[d]) * Ae[(size_t)d * 8];
        acc += __shfl_xor(acc, 1);
        if (dh == 0) down[m][r] = acc;
    }
    __syncthreads();
    for (int ci = 0; ci < 4; ci++) {
        int col = tid + ci * 256;
        float br[8];
        for (int r = 0; r < 8; r++) br[r] = lB[((size_t)e * 8 + r) * D_ + col];
        for (int m = 0; m < 16; m++) {
            float acc = 0.f;
            for (int r = 0; r < 8; r++) acc += down[m][r] * br[r];
            outp[(size_t)(tok0 + m) * D_ + col] += acc * 0.125f;
        }
    }
}

extern "C" void kernel_launch(void* const* d_in, const int* in_sizes, int n_in,
                              void* d_out, int out_size, void* d_ws, size_t ws_size,
                              hipStream_t stream) {
    const float* s      = (const float*)d_in[0];
    const float* mask   = (const float*)d_in[1];
    const float* g1     = (const float*)d_in[2];
    const float* b1     = (const float*)d_in[3];
    const float* w_qkv  = (const float*)d_in[4];
    const float* b_qkv  = (const float*)d_in[5];
    const float* w_proj = (const float*)d_in[6];
    const float* b_proj = (const float*)d_in[7];
    const float* g2     = (const float*)d_in[8];
    const float* b2     = (const float*)d_in[9];
    const float* w_fc1  = (const float*)d_in[10];
    const float* b_fc1  = (const float*)d_in[11];
    const float* w_fc2  = (const float*)d_in[12];
    const float* b_fc2  = (const float*)d_in[13];
    const float* lA     = (const float*)d_in[14];
    const float* lB     = (const float*)d_in[15];
    const int*   eidx   = (const int*)d_in[16];
    float* out = (float*)d_out;
    char* ws = (char*)d_ws;

    // workspace layout (max 115 MB, lifetime-based reuse)
    u16*   wqkvT = (u16*)(ws + 0);            // 6.0 MB
    u16*   wprojT= (u16*)(ws + 6291456);      // 2.0 MB
    u16*   wfc1T = (u16*)(ws + 8388608);      // 8.0 MB
    u16*   wfc2T = (u16*)(ws + 16777216);     // 8.0 MB
    float* s1    = (float*)(ws + 25165824);   // 26 MB f32, ends 50 MB
    u16*   xln   = (u16*)(ws + 52428800);     // 13 MB (x_ln -> o -> s_norm)
    u16*   vt    = (u16*)(ws + 66060288);     // 13 MB (v_t; dead after attn)
    u16*   qkv   = (u16*)(ws + 79691776);     // 39 MB (qkv; dead after attn)
    u16*   h     = (u16*)(ws + 66060288);     // 54.5 MB (overwrites vt+qkv), ends ~115 MB

    wtrans_all<<<12288, 256, 0, stream>>>(w_qkv, w_proj, w_fc1, w_fc2,
                                          wqkvT, wprojT, wfc1T, wfc2T);
    ln_kernel<<<NT_, 256, 0, stream>>>(s, g1, b1, xln);
    gemm5<0><<<dim3(3072 / 256, NT_ / 256), 512, 0, stream>>>(xln, wqkvT, b_qkv, qkv, NT_, 3072, 1024);
    vtrans_kernel<<<dim3(26, 128), 256, 0, stream>>>(qkv, vt);
    attn_kernel<<<dim3(7, 128), 512, 0, stream>>>(qkv, vt, mask, xln);
    gemm3<128, 128, 2, 2, 1><<<dim3(1024 / 128, NT_ / 128), 256, 0, stream>>>(xln, wprojT, b_proj, s, s1, NT_, 1024, 1024);
    ln_kernel<<<NT_, 256, 0, stream>>>(s1, g2, b2, xln);
    gemm5<2><<<dim3(4096 / 256, NT_ / 256), 512, 0, stream>>>(xln, wfc1T, b_fc1, h, NT_, 4096, 1024);
    gemm3<128, 128, 2, 2, 1><<<dim3(1024 / 128, NT_ / 128), 256, 0, stream>>>(h, wfc2T, b_fc2, s1, out, NT_, 1024, 4096);
    lora_kernel<<<128, 256, 0, stream>>>(xln, lA, lB, eidx, out);
}